// Round 11
// baseline (123.120 us; speedup 1.0000x reference)
//
#include <hip/hip_runtime.h>
#include <hip/hip_bf16.h>
#include <hip/hip_cooperative_groups.h>

// B=4, S=512, H=128
// out[b,i,h] = tanh( (1/L_b) * sum_j m_i*m_j * inp[b,j,h] * sigmoid(g0[b,i,h]+g1[b,j,h]) )
// re1 = exp(-g1); x*sigmoid = x - x*re1/(re1 + e0), e0 = exp(g0)
// SINGLE cooperative kernel, 256 blocks x 1024 threads (1 block/CU always
// schedulable -> cooperative launch cannot be occupancy-rejected).
// Phase A: gates GEMV (panel-staged swizzled W in LDS, wave-uniform x loads,
//          4-way k-split + LDS reduce), blocks 0-3 also do mask compaction.
// grid.sync()
// Phase B: pairwise loop, load-balanced grid-stride over active quads.

#define BB 4
#define SS 512
#define HH 128
#define L2E 1.44269504088896f
#define GRID 256

namespace cg = cooperative_groups;

__global__ __launch_bounds__(1024) void fused(const float* __restrict__ inp,
                                              const int* __restrict__ masks,
                                              const float* __restrict__ W0,
                                              const float* __restrict__ b0,
                                              const float* __restrict__ W1,
                                              const float* __restrict__ b1,
                                              float* __restrict__ E0,
                                              float2* __restrict__ XE,
                                              int* __restrict__ valid_idx,
                                              int* __restrict__ nvalid,
                                              float* __restrict__ rcpL,
                                              float* __restrict__ out) {
    __shared__ __align__(16) char smem[32768];   // 32 KB, aliased per phase

    const int bid = blockIdx.x;      // 256 blocks
    const int tid = threadIdx.x;     // 1024 threads

    // ================= phase A: gates + exp + pack =================
    {
        float4* sW4 = (float4*)smem;             // [(g*8+q)][o^q], 32 KB
        const int o = tid & 127;
        const int g = (tid >> 7) & 1;
        const int ks = tid >> 8;                 // 0..3 (k-quarter)
        const int r0 = bid * 8;                  // 8 global rows per block

        float acc[8] = {0.f, 0.f, 0.f, 0.f, 0.f, 0.f, 0.f, 0.f};

#pragma unroll
        for (int p = 0; p < 4; ++p) {            // 4 k-panels of 32
            if (p) __syncthreads();              // guard sW4 reuse
            // stage panel p of W0+W1: 2048 f4, 2 per thread
#pragma unroll
            for (int i = 0; i < 2; ++i) {
                const int idx = i * 1024 + tid;
                const int gs = idx >> 10;
                const int os = (idx >> 3) & 127;
                const int qs = idx & 7;
                const float* __restrict__ Wg = gs ? W1 : W0;
                sW4[(gs * 8 + qs) * 128 + (os ^ qs)] =
                    *(const float4*)(Wg + (size_t)os * HH + p * 32 + qs * 4);
            }
            __syncthreads();
            // compute: 2 q's per thread, 8 rows, x wave-uniform
#pragma unroll
            for (int qq = 0; qq < 2; ++qq) {
                const int q = ks * 2 + qq;
                const float4 w = sW4[(g * 8 + q) * 128 + (o ^ q)];
#pragma unroll
                for (int r = 0; r < 8; ++r) {
                    const float4 x = *(const float4*)(inp + (size_t)(r0 + r) * HH + p * 32 + q * 4);
                    float a = acc[r];
                    a = fmaf(x.x, w.x, a);
                    a = fmaf(x.y, w.y, a);
                    a = fmaf(x.z, w.z, a);
                    a = fmaf(x.w, w.w, a);
                    acc[r] = a;
                }
            }
        }

        // k-split reduction via LDS (alias sW4 space): [ks*2+g][r][o]
        __syncthreads();
        float* sp = (float*)smem;                // 4*2*8*128 = 8192 floats = 32 KB
#pragma unroll
        for (int r = 0; r < 8; ++r)
            sp[((ks * 2 + g) * 8 + r) * 128 + o] = acc[r];
        __syncthreads();

        // reducer: each thread finishes 2 rows for its (g2, o2)
        {
            const int o2 = tid & 127;
            const int g2 = (tid >> 7) & 1;
            const int r2 = tid >> 8;             // 0..3
            const float bias = (g2 ? b1 : b0)[o2];
#pragma unroll
            for (int rr = r2; rr < 8; rr += 4) {
                const int grow = r0 + rr;
                float s = bias;
#pragma unroll
                for (int k = 0; k < 4; ++k)
                    s += sp[((k * 2 + g2) * 8 + rr) * 128 + o2];
                const size_t idx = (size_t)grow * HH + o2;
                if (g2 == 0) {
                    E0[idx] = __builtin_amdgcn_exp2f(s * L2E);
                    if (masks[grow] == 0) out[idx] = 0.0f;
                } else {
                    const float re1 = __builtin_amdgcn_exp2f(-s * L2E); // exp(-g1)
                    XE[idx] = make_float2(inp[idx], re1);
                }
            }
        }

        // compaction: blocks 0..3, wave 0 handles batch=bid
        if (bid < BB && tid < 64) {
            const int lane = tid, b = bid;
            int base = 0;
            for (int c = 0; c < SS; c += 64) {
                int m = masks[b * SS + c + lane];
                unsigned long long bits = __ballot(m != 0);
                int pos = __popcll(bits & ((1ull << lane) - 1ull));
                if (m) valid_idx[b * SS + base + pos] = c + lane;
                base += __popcll(bits);
            }
            if (lane == 0) {
                nvalid[b] = base;
                rcpL[b] = base ? 1.0f / (float)base : 0.0f;
            }
        }
    }

    __threadfence();
    cg::this_grid().sync();

    // ================= phase B: pairwise + reduce + tanh =================
    {
        float (*red)[4][HH] = (float (*)[4][HH])smem;        // 16 KB
        int* s_vj = (int*)(smem + 16384);                    // 2 KB

        const int h = tid & 127;
        const int oc = tid >> 7;

        // quad prefix over batches (all wave-uniform scalar loads)
        int nvb[BB], P[BB + 1];
        P[0] = 0;
#pragma unroll
        for (int b = 0; b < BB; ++b) {
            nvb[b] = nvalid[b];
            P[b + 1] = P[b] + ((nvb[b] + 3) >> 2);
        }
        const int totq = P[BB];

        for (int tq = bid; tq < totq; tq += GRID) {
            int b = 0;
#pragma unroll
            for (int k = 1; k < BB; ++k) b += (tq >= P[k]);
            const int nv = nvb[b];
            const int p0 = (tq - P[b]) * 4;

            __syncthreads();                     // protect smem reuse across tq
            if (tid < nv) s_vj[tid] = valid_idx[b * SS + tid];
            __syncthreads();

            const size_t boff = (size_t)b * SS * HH;
            const float* __restrict__ E0b = E0 + boff;
            const float2* __restrict__ XEb = XE + boff;

            float e0r[4];
#pragma unroll
            for (int r = 0; r < 4; ++r)
                e0r[r] = (p0 + r < nv) ? E0b[(size_t)s_vj[p0 + r] * HH + h] : 0.0f;

            const int chunk = (nv + 7) >> 3;
            const int jb = oc * chunk;
            const int je = min(nv, jb + chunk);

            // x*sigma = x - xr*rcp(re1+e0), xr = x*re1 (shared over 4 chains)
            float acc[4] = {0.f, 0.f, 0.f, 0.f};
            float sumx = 0.f;
#pragma unroll 8
            for (int t = jb; t < je; ++t) {
                const int j = s_vj[t];
                const float2 v = XEb[(size_t)j * HH + h];  // {x, re1}
                const float x = v.x, re1 = v.y;
                sumx += x;
                const float xr = x * re1;
#pragma unroll
                for (int r = 0; r < 4; ++r)
                    acc[r] = fmaf(xr, __builtin_amdgcn_rcpf(re1 + e0r[r]), acc[r]);
            }

#pragma unroll
            for (int r = 0; r < 4; ++r) red[oc][r][h] = sumx - acc[r];
            __syncthreads();

            if (tid < 512) {
                const int r = tid >> 7;
                if (p0 + r < nv) {
                    const int hh = tid & 127;
                    float s = 0.f;
#pragma unroll
                    for (int q = 0; q < 8; ++q) s += red[q][r][hh];
                    float x = s * rcpL[b];
                    x = fminf(fmaxf(x, -30.0f), 30.0f);
                    const float e = __builtin_amdgcn_exp2f(x * 2.885390081777927f); // exp(2x)
                    const float th = (e - 1.0f) * __builtin_amdgcn_rcpf(e + 1.0f);
                    out[boff + (size_t)s_vj[p0 + r] * HH + hh] = th;
                }
            }
        }
    }
}

extern "C" void kernel_launch(void* const* d_in, const int* in_sizes, int n_in,
                              void* d_out, int out_size, void* d_ws, size_t ws_size,
                              hipStream_t stream) {
    const float* inp = (const float*)d_in[0];
    const int* masks = (const int*)d_in[1];
    const float* W0 = (const float*)d_in[2];
    const float* b0 = (const float*)d_in[3];
    const float* W1 = (const float*)d_in[4];
    const float* b1 = (const float*)d_in[5];
    float* out = (float*)d_out;

    const size_t nBSH = (size_t)BB * SS * HH;  // 262144
    float* E0 = (float*)d_ws;                  // 1 MB
    float2* XE = (float2*)(E0 + nBSH);         // 2 MB
    int* valid_idx = (int*)(XE + nBSH);        // 8 KB
    int* nvalid = valid_idx + BB * SS;
    float* rcpL = (float*)(nvalid + BB);

    void* args[] = {(void*)&inp, (void*)&masks, (void*)&W0, (void*)&b0,
                    (void*)&W1, (void*)&b1, (void*)&E0, (void*)&XE,
                    (void*)&valid_idx, (void*)&nvalid, (void*)&rcpL, (void*)&out};
    hipLaunchCooperativeKernel((void*)fused, dim3(GRID), dim3(1024), args, 0, stream);
}